// Round 4
// baseline (1188.162 us; speedup 1.0000x reference)
//
#include <hip/hip_runtime.h>

#define B_ 8
#define H_ 128
#define W_ 128
#define C_ 128

using f32x4 = __attribute__((ext_vector_type(4))) float;
using s16x8 = __attribute__((ext_vector_type(8))) short;

// mish(x) = x * tanh(softplus(x)) = x * (t^2 + 2t) / (t^2 + 2t + 2), t = e^x
__device__ __forceinline__ float mish_f(float x) {
    float t = __expf(fminf(x, 20.0f));
    float u = t * (t + 2.0f);
    return x * u / (u + 2.0f);
}

__device__ __forceinline__ int swz_row(int blk) {
    return ((blk & 7) << 7) | (blk >> 3);
}

// fp32 -> bf16 round-to-nearest-even on raw bits
__device__ __forceinline__ unsigned short f2bf_rne(float x) {
    unsigned u = __builtin_bit_cast(unsigned, x);
    u += 0x7FFFu + ((u >> 16) & 1u);
    return (unsigned short)(u >> 16);
}
__device__ __forceinline__ float bf2f(unsigned short h) {
    unsigned u = ((unsigned)h) << 16;
    return __builtin_bit_cast(float, u);
}

// ---------------------------------------------------------------------------
// 1) bilinear backward warp
// ---------------------------------------------------------------------------
__global__ __launch_bounds__(256) void warp_kernel(
    const float* __restrict__ nxt, const float* __restrict__ flo,
    float* __restrict__ nxtw)
{
    const int tid = threadIdx.x;
    const int c   = tid & 127;
    const int pix = blockIdx.x * 2 + (tid >> 7);
    const int b   = pix >> 14;
    const int rem = pix & 16383;
    const int y   = rem >> 7;
    const int x   = rem & 127;

    const float fx = flo[(size_t)pix * 2 + 0];
    const float fy = flo[(size_t)pix * 2 + 1];
    const float xf = (float)x + fx;
    const float yf = (float)y + fy;
    const int x0 = (int)xf;
    const int y0 = (int)yf;
    const int x0c = min(max(x0, 0), W_ - 1);
    const int x1c = min(max(x0 + 1, 0), W_ - 1);
    const int y0c = min(max(y0, 0), H_ - 1);
    const int y1c = min(max(y0 + 1, 0), H_ - 1);
    const float x0f = (float)x0c, x1f = (float)x1c;
    const float y0f = (float)y0c, y1f = (float)y1c;
    const float wa = (x1f - xf) * (y1f - yf);
    const float wb = (x1f - xf) * (yf - y0f);
    const float wc = (xf - x0f) * (y1f - yf);
    const float wd = (xf - x0f) * (yf - y0f);

    const float* base = nxt + (size_t)b * H_ * W_ * C_;
    const float Ia = base[((size_t)y0c * W_ + x0c) * C_ + c];
    const float Ib = base[((size_t)y1c * W_ + x0c) * C_ + c];
    const float Ic = base[((size_t)y0c * W_ + x1c) * C_ + c];
    const float Id = base[((size_t)y1c * W_ + x1c) * C_ + c];
    nxtw[(size_t)pix * C_ + c] = wa * Ia + wb * Ib + wc * Ic + wd * Id;
}

// ---------------------------------------------------------------------------
// 2) cost volume (R2 design — not the bottleneck)
// ---------------------------------------------------------------------------
__global__ __launch_bounds__(576, 3) void costvol_kernel(
    const float* __restrict__ prv, const float* __restrict__ nxtw,
    float* __restrict__ cost)
{
    constexpr int KC   = 8;
    constexpr int NSTR = 144;
    constexpr int PSTR = 132;
    __shared__ float NL[9][KC][NSTR];
    __shared__ float PL[KC][PSTR];

    const int tid  = threadIdx.x;
    const int w    = tid >> 6;
    const int lane = tid & 63;
    const int dy   = w - 4;
    const int r    = swz_row(blockIdx.x);
    const int y    = r & 127;
    const int b    = r >> 7;
    const int q    = y + dy;
    const bool valid = (q >= 0) && (q < H_);

    const int cs = lane & 3;
    const int xg = lane >> 2;
    const int x0 = xg * 8;

    const int scl = lane & 7;
    const int sxq = lane >> 3;
    const float* nrow = nxtw + ((size_t)(b * H_ + q) * W_) * C_;
    const int ppc = tid & 7;
    const int ppq = tid >> 3;

    float acc[8][9];
    #pragma unroll
    for (int i = 0; i < 8; ++i)
        #pragma unroll
        for (int d = 0; d < 9; ++d) acc[i][d] = 0.0f;

    float nv[5][4];
    float pv4[4];

    {
        const int c0 = 0;
        if (valid) {
            #pragma unroll
            for (int p = 0; p < 5; ++p) {
                const int xh0 = p * 32 + sxq * 4;
                if (xh0 < 140) {
                    #pragma unroll
                    for (int t = 0; t < 4; ++t) {
                        const int xs = xh0 + t - 4;
                        nv[p][t] = (xs >= 0 && xs < W_)
                                 ? nrow[(size_t)xs * C_ + c0 + scl] : 0.0f;
                    }
                }
            }
        }
        if (tid < 256) {
            #pragma unroll
            for (int t = 0; t < 4; ++t)
                pv4[t] = prv[((size_t)r * W_ + ppq * 4 + t) * C_ + c0 + ppc];
        }
    }

    for (int cc = 0; cc < 16; ++cc) {
        __syncthreads();
        if (valid) {
            #pragma unroll
            for (int p = 0; p < 5; ++p) {
                const int xh0 = p * 32 + sxq * 4;
                if (xh0 < 140)
                    *(float4*)&NL[w][scl][xh0] =
                        make_float4(nv[p][0], nv[p][1], nv[p][2], nv[p][3]);
            }
        }
        if (tid < 256)
            *(float4*)&PL[ppc][ppq * 4] =
                make_float4(pv4[0], pv4[1], pv4[2], pv4[3]);
        __syncthreads();

        if (cc < 15) {
            const int c0 = (cc + 1) * KC;
            if (valid) {
                #pragma unroll
                for (int p = 0; p < 5; ++p) {
                    const int xh0 = p * 32 + sxq * 4;
                    if (xh0 < 140) {
                        #pragma unroll
                        for (int t = 0; t < 4; ++t) {
                            const int xs = xh0 + t - 4;
                            nv[p][t] = (xs >= 0 && xs < W_)
                                     ? nrow[(size_t)xs * C_ + c0 + scl] : 0.0f;
                        }
                    }
                }
            }
            if (tid < 256) {
                #pragma unroll
                for (int t = 0; t < 4; ++t)
                    pv4[t] = prv[((size_t)r * W_ + ppq * 4 + t) * C_ + c0 + ppc];
            }
        }

        if (valid) {
            #pragma unroll
            for (int j = 0; j < 2; ++j) {
                const int c = cs + 4 * j;
                float pv[8];
                {
                    float4 p0 = *(const float4*)&PL[c][x0];
                    float4 p1 = *(const float4*)&PL[c][x0 + 4];
                    pv[0]=p0.x; pv[1]=p0.y; pv[2]=p0.z; pv[3]=p0.w;
                    pv[4]=p1.x; pv[5]=p1.y; pv[6]=p1.z; pv[7]=p1.w;
                }
                float n[16];
                {
                    float4 n0 = *(const float4*)&NL[w][c][x0];
                    float4 n1 = *(const float4*)&NL[w][c][x0 + 4];
                    float4 n2 = *(const float4*)&NL[w][c][x0 + 8];
                    float4 n3 = *(const float4*)&NL[w][c][x0 + 12];
                    n[0]=n0.x;  n[1]=n0.y;  n[2]=n0.z;  n[3]=n0.w;
                    n[4]=n1.x;  n[5]=n1.y;  n[6]=n1.z;  n[7]=n1.w;
                    n[8]=n2.x;  n[9]=n2.y;  n[10]=n2.z; n[11]=n2.w;
                    n[12]=n3.x; n[13]=n3.y; n[14]=n3.z; n[15]=n3.w;
                }
                #pragma unroll
                for (int i = 0; i < 8; ++i)
                    #pragma unroll
                    for (int d = 0; d < 9; ++d)
                        acc[i][d] += pv[i] * n[i + d];
            }
        }
    }

    #pragma unroll
    for (int i = 0; i < 8; ++i)
        #pragma unroll
        for (int d = 0; d < 9; ++d) {
            float v = acc[i][d];
            v += __shfl_xor(v, 1);
            v += __shfl_xor(v, 2);
            acc[i][d] = v;
        }
    if (cs == 0) {
        #pragma unroll
        for (int i = 0; i < 8; ++i) {
            const size_t base = ((size_t)r * W_ + (x0 + i)) * 81 + (size_t)(dy + 4) * 9;
            #pragma unroll
            for (int d = 0; d < 9; ++d)
                cost[base + d] = valid ? acc[i][d] * (1.0f / 128.0f) : 0.0f;
        }
    }
}

// ---------------------------------------------------------------------------
// 3) weight prep: pw[CIN][COUT] fp32 -> bf16 hi/lo B-frag tiles
//    layout [kt*NT+nt][n(16)][k(32)], zero-padded
// ---------------------------------------------------------------------------
__global__ __launch_bounds__(256) void prep_kernel(
    const float* __restrict__ pw, int CIN, int COUT, int NT,
    unsigned short* __restrict__ hi, unsigned short* __restrict__ lo)
{
    const int kt = blockIdx.x / NT;
    const int nt = blockIdx.x - kt * NT;
    #pragma unroll
    for (int s = 0; s < 2; ++s) {
        const int e = threadIdx.x + 256 * s;
        const int n = e >> 5, k = e & 31;
        const int kg = kt * 32 + k, ng = nt * 16 + n;
        const float v = (kg < CIN && ng < COUT) ? pw[(size_t)kg * COUT + ng] : 0.0f;
        const unsigned short h = f2bf_rne(v);
        const unsigned short l = f2bf_rne(v - bf2f(h));
        const size_t o = ((size_t)blockIdx.x * 16 + n) * 32 + k;
        hi[o] = h; lo[o] = l;
    }
}

// ---------------------------------------------------------------------------
// 4) fused depthwise3x3(fp32, global-direct taps) + pointwise MFMA (bf16 hi/lo)
// One block per (b,h) row. Depthwise tasks (R2 pattern, proven 68MB fetch):
// task = (channel-in-chunk, 4px group), taps read straight from global
// (lane-contiguous in channel), result converted to bf16 hi/lo and written
// directly into the A-fragment LDS (2B writes, <=2-way aliasing).
// MFMA: wave w -> M-tiles {2w,2w+1} x NT N-tiles, 3 MFMAs (hi*hi,hi*lo,lo*hi).
// ---------------------------------------------------------------------------
template<int CIN, bool IS_L0>
__device__ __forceinline__ float read_x(const float* __restrict__ in,
    const float* __restrict__ cost, const float* __restrict__ prv,
    const float* __restrict__ flo, int b, int y, int x, int c)
{
    const size_t p = ((size_t)b * H_ + y) * W_ + x;
    if constexpr (IS_L0) {
        if (c < 81)  return cost[p * 81 + c];
        if (c < 209) return prv[p * 128 + (c - 81)];
        return flo[p * 2 + (c - 209)];
    } else {
        return in[p * CIN + c];
    }
}

template<int CIN, int COUT, bool ACT, bool IS_L0>
__global__ __launch_bounds__(256, 3) void sepconv_kernel(
    const float* __restrict__ in,
    const float* __restrict__ cost, const float* __restrict__ prv,
    const float* __restrict__ flo,
    const float* __restrict__ dw,
    const unsigned short* __restrict__ Bhi, const unsigned short* __restrict__ Blo,
    const float* __restrict__ bias, float* __restrict__ out)
{
    constexpr int KT   = (CIN + 31) / 32;
    constexpr int KPAD = KT * 32;
    constexpr int NT   = (COUT + 15) / 16;
    constexpr int KSTR = 40;                 // ushort stride per px (80B, 16B-mult)
    __shared__ unsigned short Ahi[128 * KSTR];   // 10240 B
    __shared__ unsigned short Alo[128 * KSTR];   // 10240 B
    __shared__ float dwl[9 * KPAD];              // <= 8064 B

    const int tid  = threadIdx.x;
    const int lane = tid & 63;
    const int w    = tid >> 6;
    const int r    = swz_row(blockIdx.x);    // b*H + h
    const int h    = r & 127;
    const int b    = r >> 7;

    // stage all depthwise weights once (zero-padded channels)
    for (int i = tid; i < 9 * KPAD; i += 256) {
        const int t = i / KPAD, c = i - t * KPAD;
        dwl[i] = (c < CIN) ? dw[t * CIN + c] : 0.0f;
    }

    f32x4 acc[2][NT];
    #pragma unroll
    for (int m = 0; m < 2; ++m)
        #pragma unroll
        for (int n = 0; n < NT; ++n)
            acc[m][n] = (f32x4){0.0f, 0.0f, 0.0f, 0.0f};

    for (int kt = 0; kt < KT; ++kt) {
        __syncthreads();                     // dwl ready / prev MFMA A-reads done

        // depthwise: 4 tasks/thread; task = (c in [0,32), 4-px group)
        #pragma unroll
        for (int s = 0; s < 4; ++s) {
            const int e   = tid + 256 * s;
            const int c   = e & 31;
            const int pxg = e >> 5;
            const int xb  = pxg * 4;
            const int cg  = kt * 32 + c;
            float wreg[9];
            #pragma unroll
            for (int t9 = 0; t9 < 9; ++t9)
                wreg[t9] = dwl[t9 * KPAD + kt * 32 + c];
            float a[4] = {0.f, 0.f, 0.f, 0.f};
            #pragma unroll
            for (int ky = 0; ky < 3; ++ky) {
                const int yy = h + ky - 1;
                bool yok = (yy >= 0) & (yy < H_);
                if constexpr (CIN % 32 != 0) yok = yok & (cg < CIN);
                #pragma unroll
                for (int m = 0; m < 6; ++m) {
                    const int xx = xb - 1 + m;
                    const bool ok = yok & (xx >= 0) & (xx < W_);
                    const float v = ok ? read_x<CIN, IS_L0>(in, cost, prv, flo, b, yy, xx, cg) : 0.0f;
                    #pragma unroll
                    for (int kx = 0; kx < 3; ++kx) {
                        const int i = m - kx;
                        if (i >= 0 && i < 4) a[i] += wreg[ky * 3 + kx] * v;
                    }
                }
            }
            #pragma unroll
            for (int i = 0; i < 4; ++i) {
                const unsigned short hh = f2bf_rne(a[i]);
                const unsigned short ll = f2bf_rne(a[i] - bf2f(hh));
                Ahi[(xb + i) * KSTR + c] = hh;
                Alo[(xb + i) * KSTR + c] = ll;
            }
        }
        __syncthreads();                     // A ready for this 32-chunk

        // MFMA sweep: wave w -> M-tiles {2w, 2w+1}
        s16x8 ahi[2], alo[2];
        #pragma unroll
        for (int mtl = 0; mtl < 2; ++mtl) {
            const int m  = (2 * w + mtl) * 16 + (lane & 15);
            const int ko = (lane >> 4) * 8;
            ahi[mtl] = *(const s16x8*)&Ahi[m * KSTR + ko];
            alo[mtl] = *(const s16x8*)&Alo[m * KSTR + ko];
        }
        #pragma unroll
        for (int nt = 0; nt < NT; ++nt) {
            const size_t boff = (((size_t)(kt * NT + nt)) * 16 + (lane & 15)) * 32
                              + (lane >> 4) * 8;
            const s16x8 bhi = *(const s16x8*)&Bhi[boff];
            const s16x8 blo = *(const s16x8*)&Blo[boff];
            #pragma unroll
            for (int mtl = 0; mtl < 2; ++mtl) {
                acc[mtl][nt] = __builtin_amdgcn_mfma_f32_16x16x32_bf16(alo[mtl], bhi, acc[mtl][nt], 0, 0, 0);
                acc[mtl][nt] = __builtin_amdgcn_mfma_f32_16x16x32_bf16(ahi[mtl], blo, acc[mtl][nt], 0, 0, 0);
                acc[mtl][nt] = __builtin_amdgcn_mfma_f32_16x16x32_bf16(ahi[mtl], bhi, acc[mtl][nt], 0, 0, 0);
            }
        }
    }

    // epilogue: C/D layout col=lane&15 (n), row=quad*4+reg (px within tile)
    const int n    = lane & 15;
    const int quad = lane >> 4;
    #pragma unroll
    for (int mtl = 0; mtl < 2; ++mtl) {
        #pragma unroll
        for (int nt = 0; nt < NT; ++nt) {
            const int o = nt * 16 + n;
            if ((COUT % 16 == 0) || (o < COUT)) {
                const float bv = ACT ? bias[o] : 0.0f;   // L5 has no bias
                #pragma unroll
                for (int reg = 0; reg < 4; ++reg) {
                    const int px = (2 * w + mtl) * 16 + quad * 4 + reg;
                    const float v = acc[mtl][nt][reg] + bv;
                    out[((size_t)r * W_ + px) * COUT + o] = ACT ? mish_f(v) : v;
                }
            }
        }
    }
}

// ---------------------------------------------------------------------------
extern "C" void kernel_launch(void* const* d_in, const int* in_sizes, int n_in,
                              void* d_out, int out_size, void* d_ws, size_t ws_size,
                              hipStream_t stream)
{
    (void)in_sizes; (void)n_in; (void)out_size; (void)ws_size;
    const float* prv = (const float*)d_in[0];
    const float* nxt = (const float*)d_in[1];
    const float* flo = (const float*)d_in[2];
    const float* dw0 = (const float*)d_in[3];
    const float* pw0 = (const float*)d_in[4];
    const float* b0  = (const float*)d_in[5];
    const float* dw1 = (const float*)d_in[6];
    const float* pw1 = (const float*)d_in[7];
    const float* b1  = (const float*)d_in[8];
    const float* dw2 = (const float*)d_in[9];
    const float* pw2 = (const float*)d_in[10];
    const float* b2  = (const float*)d_in[11];
    const float* dw3 = (const float*)d_in[12];
    const float* pw3 = (const float*)d_in[13];
    const float* b3  = (const float*)d_in[14];
    const float* dw4 = (const float*)d_in[15];
    const float* pw4 = (const float*)d_in[16];
    const float* b4  = (const float*)d_in[17];
    const float* dw5 = (const float*)d_in[18];
    const float* pw5 = (const float*)d_in[19];

    char* ws = (char*)d_ws;
    float* bufA = (float*)ws;                               // [0, 64Mi)
    float* bufC = (float*)(ws + 67108864);                  // [64Mi, 128Mi)
    float* costb = bufC;                                    // 42.47 MB
    float* l4out = (float*)(ws + 67108864 + 33554432);      // bufC + 32Mi (16 MB)
    float* outp  = (float*)d_out;

    // weight regions (bf16 hi/lo tile arrays)
    unsigned short* W0h = (unsigned short*)(ws + 112000000);            // 57344 B
    unsigned short* W0l = (unsigned short*)(ws + 112000000 + 57344);
    unsigned short* W1h = (unsigned short*)d_out;                       // 32768 B
    unsigned short* W1l = (unsigned short*)d_out + 16384;
    unsigned short* W2h = (unsigned short*)(ws + 50331648);             // 24576 B
    unsigned short* W2l = (unsigned short*)(ws + 50356224);
    unsigned short* W3h = (unsigned short*)(ws + 50380800);             // 12288 B
    unsigned short* W3l = (unsigned short*)(ws + 50393088);
    unsigned short* W4h = (unsigned short*)(ws + 50405376);             //  4096 B
    unsigned short* W4l = (unsigned short*)(ws + 50409472);
    unsigned short* W5h = (unsigned short*)(ws + 50413568);             //  1024 B
    unsigned short* W5l = (unsigned short*)(ws + 50414592);

    const float* nullf = nullptr;

    warp_kernel<<<65536, 256, 0, stream>>>(nxt, flo, bufA);
    costvol_kernel<<<1024, 576, 0, stream>>>(prv, bufA, costb);

    prep_kernel<<<7 * 8, 256, 0, stream>>>(pw0, 211, 128, 8, W0h, W0l);
    prep_kernel<<<4 * 8, 256, 0, stream>>>(pw1, 128, 128, 8, W1h, W1l);

    // L0: 211 -> 128, reads [cost|prv|flo], writes bufA (nxtw dead)
    sepconv_kernel<211, 128, true,  true ><<<1024, 256, 0, stream>>>(
        nullf, costb, prv, flo, dw0, W0h, W0l, b0, bufA);
    // L1: 128 -> 128, bufA -> bufC (cost + W0 dead)
    sepconv_kernel<128, 128, true,  false><<<1024, 256, 0, stream>>>(
        bufA, nullf, nullf, nullf, dw1, W1h, W1l, b1, bufC);

    // bufA now dead -> prep remaining weights into its tail
    prep_kernel<<<4 * 6, 256, 0, stream>>>(pw2, 128,  96, 6, W2h, W2l);
    prep_kernel<<<3 * 4, 256, 0, stream>>>(pw3,  96,  64, 4, W3h, W3l);
    prep_kernel<<<2 * 2, 256, 0, stream>>>(pw4,  64,  32, 2, W4h, W4l);
    prep_kernel<<<1 * 1, 256, 0, stream>>>(pw5,  32,   2, 1, W5h, W5l);

    // L2: 128 -> 96, bufC -> bufA[0,48Mi)
    sepconv_kernel<128,  96, true,  false><<<1024, 256, 0, stream>>>(
        bufC, nullf, nullf, nullf, dw2, W2h, W2l, b2, bufA);
    // L3: 96 -> 64, bufA -> bufC[0,32Mi) (L1 out dead)
    sepconv_kernel< 96,  64, true,  false><<<1024, 256, 0, stream>>>(
        bufA, nullf, nullf, nullf, dw3, W3h, W3l, b3, bufC);
    // L4: 64 -> 32, bufC[0,32Mi) -> bufC[32Mi,48Mi)
    sepconv_kernel< 64,  32, true,  false><<<1024, 256, 0, stream>>>(
        bufC, nullf, nullf, nullf, dw4, W4h, W4l, b4, l4out);
    // L5: 32 -> 2, -> d_out (overwrites W1)
    sepconv_kernel< 32,   2, false, false><<<1024, 256, 0, stream>>>(
        l4out, nullf, nullf, nullf, dw5, W5h, W5l, nullf, outp);
}

// Round 5
// 985.924 us; speedup vs baseline: 1.2051x; 1.2051x over previous
//
#include <hip/hip_runtime.h>

#define B_ 8
#define H_ 128
#define W_ 128
#define C_ 128

using f32x4 = __attribute__((ext_vector_type(4))) float;
using s16x8 = __attribute__((ext_vector_type(8))) short;

// mish(x) = x * tanh(softplus(x)) = x * (t^2 + 2t) / (t^2 + 2t + 2), t = e^x
__device__ __forceinline__ float mish_f(float x) {
    float t = __expf(fminf(x, 20.0f));
    float u = t * (t + 2.0f);
    return x * u / (u + 2.0f);
}

__device__ __forceinline__ int swz_row(int blk) {
    return ((blk & 7) << 7) | (blk >> 3);
}

// fp32 -> bf16 round-to-nearest-even on raw bits
__device__ __forceinline__ unsigned short f2bf_rne(float x) {
    unsigned u = __builtin_bit_cast(unsigned, x);
    u += 0x7FFFu + ((u >> 16) & 1u);
    return (unsigned short)(u >> 16);
}
__device__ __forceinline__ float bf2f(unsigned short h) {
    unsigned u = ((unsigned)h) << 16;
    return __builtin_bit_cast(float, u);
}

// ---------------------------------------------------------------------------
// 1) bilinear backward warp
// ---------------------------------------------------------------------------
__global__ __launch_bounds__(256) void warp_kernel(
    const float* __restrict__ nxt, const float* __restrict__ flo,
    float* __restrict__ nxtw)
{
    const int tid = threadIdx.x;
    const int c   = tid & 127;
    const int pix = blockIdx.x * 2 + (tid >> 7);
    const int b   = pix >> 14;
    const int rem = pix & 16383;
    const int y   = rem >> 7;
    const int x   = rem & 127;

    const float fx = flo[(size_t)pix * 2 + 0];
    const float fy = flo[(size_t)pix * 2 + 1];
    const float xf = (float)x + fx;
    const float yf = (float)y + fy;
    const int x0 = (int)xf;
    const int y0 = (int)yf;
    const int x0c = min(max(x0, 0), W_ - 1);
    const int x1c = min(max(x0 + 1, 0), W_ - 1);
    const int y0c = min(max(y0, 0), H_ - 1);
    const int y1c = min(max(y0 + 1, 0), H_ - 1);
    const float x0f = (float)x0c, x1f = (float)x1c;
    const float y0f = (float)y0c, y1f = (float)y1c;
    const float wa = (x1f - xf) * (y1f - yf);
    const float wb = (x1f - xf) * (yf - y0f);
    const float wc = (xf - x0f) * (y1f - yf);
    const float wd = (xf - x0f) * (yf - y0f);

    const float* base = nxt + (size_t)b * H_ * W_ * C_;
    const float Ia = base[((size_t)y0c * W_ + x0c) * C_ + c];
    const float Ib = base[((size_t)y1c * W_ + x0c) * C_ + c];
    const float Ic = base[((size_t)y0c * W_ + x1c) * C_ + c];
    const float Id = base[((size_t)y1c * W_ + x1c) * C_ + c];
    nxtw[(size_t)pix * C_ + c] = wa * Ia + wb * Ib + wc * Ic + wd * Id;
}

// ---------------------------------------------------------------------------
// 2) cost volume (R2 design — not the bottleneck)
// ---------------------------------------------------------------------------
__global__ __launch_bounds__(576, 3) void costvol_kernel(
    const float* __restrict__ prv, const float* __restrict__ nxtw,
    float* __restrict__ cost)
{
    constexpr int KC   = 8;
    constexpr int NSTR = 144;
    constexpr int PSTR = 132;
    __shared__ float NL[9][KC][NSTR];
    __shared__ float PL[KC][PSTR];

    const int tid  = threadIdx.x;
    const int w    = tid >> 6;
    const int lane = tid & 63;
    const int dy   = w - 4;
    const int r    = swz_row(blockIdx.x);
    const int y    = r & 127;
    const int b    = r >> 7;
    const int q    = y + dy;
    const bool valid = (q >= 0) && (q < H_);

    const int cs = lane & 3;
    const int xg = lane >> 2;
    const int x0 = xg * 8;

    const int scl = lane & 7;
    const int sxq = lane >> 3;
    const float* nrow = nxtw + ((size_t)(b * H_ + q) * W_) * C_;
    const int ppc = tid & 7;
    const int ppq = tid >> 3;

    float acc[8][9];
    #pragma unroll
    for (int i = 0; i < 8; ++i)
        #pragma unroll
        for (int d = 0; d < 9; ++d) acc[i][d] = 0.0f;

    float nv[5][4];
    float pv4[4];

    {
        const int c0 = 0;
        if (valid) {
            #pragma unroll
            for (int p = 0; p < 5; ++p) {
                const int xh0 = p * 32 + sxq * 4;
                if (xh0 < 140) {
                    #pragma unroll
                    for (int t = 0; t < 4; ++t) {
                        const int xs = xh0 + t - 4;
                        nv[p][t] = (xs >= 0 && xs < W_)
                                 ? nrow[(size_t)xs * C_ + c0 + scl] : 0.0f;
                    }
                }
            }
        }
        if (tid < 256) {
            #pragma unroll
            for (int t = 0; t < 4; ++t)
                pv4[t] = prv[((size_t)r * W_ + ppq * 4 + t) * C_ + c0 + ppc];
        }
    }

    for (int cc = 0; cc < 16; ++cc) {
        __syncthreads();
        if (valid) {
            #pragma unroll
            for (int p = 0; p < 5; ++p) {
                const int xh0 = p * 32 + sxq * 4;
                if (xh0 < 140)
                    *(float4*)&NL[w][scl][xh0] =
                        make_float4(nv[p][0], nv[p][1], nv[p][2], nv[p][3]);
            }
        }
        if (tid < 256)
            *(float4*)&PL[ppc][ppq * 4] =
                make_float4(pv4[0], pv4[1], pv4[2], pv4[3]);
        __syncthreads();

        if (cc < 15) {
            const int c0 = (cc + 1) * KC;
            if (valid) {
                #pragma unroll
                for (int p = 0; p < 5; ++p) {
                    const int xh0 = p * 32 + sxq * 4;
                    if (xh0 < 140) {
                        #pragma unroll
                        for (int t = 0; t < 4; ++t) {
                            const int xs = xh0 + t - 4;
                            nv[p][t] = (xs >= 0 && xs < W_)
                                     ? nrow[(size_t)xs * C_ + c0 + scl] : 0.0f;
                        }
                    }
                }
            }
            if (tid < 256) {
                #pragma unroll
                for (int t = 0; t < 4; ++t)
                    pv4[t] = prv[((size_t)r * W_ + ppq * 4 + t) * C_ + c0 + ppc];
            }
        }

        if (valid) {
            #pragma unroll
            for (int j = 0; j < 2; ++j) {
                const int c = cs + 4 * j;
                float pv[8];
                {
                    float4 p0 = *(const float4*)&PL[c][x0];
                    float4 p1 = *(const float4*)&PL[c][x0 + 4];
                    pv[0]=p0.x; pv[1]=p0.y; pv[2]=p0.z; pv[3]=p0.w;
                    pv[4]=p1.x; pv[5]=p1.y; pv[6]=p1.z; pv[7]=p1.w;
                }
                float n[16];
                {
                    float4 n0 = *(const float4*)&NL[w][c][x0];
                    float4 n1 = *(const float4*)&NL[w][c][x0 + 4];
                    float4 n2 = *(const float4*)&NL[w][c][x0 + 8];
                    float4 n3 = *(const float4*)&NL[w][c][x0 + 12];
                    n[0]=n0.x;  n[1]=n0.y;  n[2]=n0.z;  n[3]=n0.w;
                    n[4]=n1.x;  n[5]=n1.y;  n[6]=n1.z;  n[7]=n1.w;
                    n[8]=n2.x;  n[9]=n2.y;  n[10]=n2.z; n[11]=n2.w;
                    n[12]=n3.x; n[13]=n3.y; n[14]=n3.z; n[15]=n3.w;
                }
                #pragma unroll
                for (int i = 0; i < 8; ++i)
                    #pragma unroll
                    for (int d = 0; d < 9; ++d)
                        acc[i][d] += pv[i] * n[i + d];
            }
        }
    }

    #pragma unroll
    for (int i = 0; i < 8; ++i)
        #pragma unroll
        for (int d = 0; d < 9; ++d) {
            float v = acc[i][d];
            v += __shfl_xor(v, 1);
            v += __shfl_xor(v, 2);
            acc[i][d] = v;
        }
    if (cs == 0) {
        #pragma unroll
        for (int i = 0; i < 8; ++i) {
            const size_t base = ((size_t)r * W_ + (x0 + i)) * 81 + (size_t)(dy + 4) * 9;
            #pragma unroll
            for (int d = 0; d < 9; ++d)
                cost[base + d] = valid ? acc[i][d] * (1.0f / 128.0f) : 0.0f;
        }
    }
}

// ---------------------------------------------------------------------------
// 3) weight prep: pw[CIN][COUT] fp32 -> bf16 hi/lo B-frag tiles
//    layout [kt*NT+nt][n(16)][k(32)], zero-padded
// ---------------------------------------------------------------------------
__global__ __launch_bounds__(256) void prep_kernel(
    const float* __restrict__ pw, int CIN, int COUT, int NT,
    unsigned short* __restrict__ hi, unsigned short* __restrict__ lo)
{
    const int kt = blockIdx.x / NT;
    const int nt = blockIdx.x - kt * NT;
    #pragma unroll
    for (int s = 0; s < 2; ++s) {
        const int e = threadIdx.x + 256 * s;
        const int n = e >> 5, k = e & 31;
        const int kg = kt * 32 + k, ng = nt * 16 + n;
        const float v = (kg < CIN && ng < COUT) ? pw[(size_t)kg * COUT + ng] : 0.0f;
        const unsigned short h = f2bf_rne(v);
        const unsigned short l = f2bf_rne(v - bf2f(h));
        const size_t o = ((size_t)blockIdx.x * 16 + n) * 32 + k;
        hi[o] = h; lo[o] = l;
    }
}

// ---------------------------------------------------------------------------
// 4) fused depthwise3x3(fp32, global-direct taps) + pointwise MFMA (bf16 hi/lo)
// One block per (b,h) row.
// launch_bounds(256,2): 2 blocks/CU — 512 resident row-blocks keep the tap
// working set within the 256 MiB LLC. (256,3) thrashed it: R3/R4 fetched
// 580-811 MB vs R2's 68 MB for identical demand. Do not raise without
// re-checking FETCH_SIZE.
// ---------------------------------------------------------------------------
template<int CIN, bool IS_L0>
__device__ __forceinline__ float read_x(const float* __restrict__ in,
    const float* __restrict__ cost, const float* __restrict__ prv,
    const float* __restrict__ flo, int b, int y, int x, int c)
{
    const size_t p = ((size_t)b * H_ + y) * W_ + x;
    if constexpr (IS_L0) {
        if (c < 81)  return cost[p * 81 + c];
        if (c < 209) return prv[p * 128 + (c - 81)];
        return flo[p * 2 + (c - 209)];
    } else {
        return in[p * CIN + c];
    }
}

template<int CIN, int COUT, bool ACT, bool IS_L0>
__global__ __launch_bounds__(256, 2) void sepconv_kernel(
    const float* __restrict__ in,
    const float* __restrict__ cost, const float* __restrict__ prv,
    const float* __restrict__ flo,
    const float* __restrict__ dw,
    const unsigned short* __restrict__ Bhi, const unsigned short* __restrict__ Blo,
    const float* __restrict__ bias, float* __restrict__ out)
{
    constexpr int KT   = (CIN + 31) / 32;
    constexpr int KPAD = KT * 32;
    constexpr int NT   = (COUT + 15) / 16;
    constexpr int KSTR = 40;                 // ushort stride per px (80B, 16B-mult)
    __shared__ unsigned short Ahi[128 * KSTR];   // 10240 B
    __shared__ unsigned short Alo[128 * KSTR];   // 10240 B
    __shared__ float dwl[9 * KPAD];              // <= 8064 B

    const int tid  = threadIdx.x;
    const int lane = tid & 63;
    const int w    = tid >> 6;
    const int r    = swz_row(blockIdx.x);    // b*H + h
    const int h    = r & 127;
    const int b    = r >> 7;

    // stage all depthwise weights once (zero-padded channels)
    for (int i = tid; i < 9 * KPAD; i += 256) {
        const int t = i / KPAD, c = i - t * KPAD;
        dwl[i] = (c < CIN) ? dw[t * CIN + c] : 0.0f;
    }

    f32x4 acc[2][NT];
    #pragma unroll
    for (int m = 0; m < 2; ++m)
        #pragma unroll
        for (int n = 0; n < NT; ++n)
            acc[m][n] = (f32x4){0.0f, 0.0f, 0.0f, 0.0f};

    for (int kt = 0; kt < KT; ++kt) {
        __syncthreads();                     // dwl ready / prev MFMA A-reads done

        // depthwise: 4 tasks/thread; task = (c in [0,32), 4-px group)
        #pragma unroll
        for (int s = 0; s < 4; ++s) {
            const int e   = tid + 256 * s;
            const int c   = e & 31;
            const int pxg = e >> 5;
            const int xb  = pxg * 4;
            const int cg  = kt * 32 + c;
            float wreg[9];
            #pragma unroll
            for (int t9 = 0; t9 < 9; ++t9)
                wreg[t9] = dwl[t9 * KPAD + kt * 32 + c];
            float a[4] = {0.f, 0.f, 0.f, 0.f};
            #pragma unroll
            for (int ky = 0; ky < 3; ++ky) {
                const int yy = h + ky - 1;
                bool yok = (yy >= 0) & (yy < H_);
                if constexpr (CIN % 32 != 0) yok = yok & (cg < CIN);
                #pragma unroll
                for (int m = 0; m < 6; ++m) {
                    const int xx = xb - 1 + m;
                    const bool ok = yok & (xx >= 0) & (xx < W_);
                    const float v = ok ? read_x<CIN, IS_L0>(in, cost, prv, flo, b, yy, xx, cg) : 0.0f;
                    #pragma unroll
                    for (int kx = 0; kx < 3; ++kx) {
                        const int i = m - kx;
                        if (i >= 0 && i < 4) a[i] += wreg[ky * 3 + kx] * v;
                    }
                }
            }
            #pragma unroll
            for (int i = 0; i < 4; ++i) {
                const unsigned short hh = f2bf_rne(a[i]);
                const unsigned short ll = f2bf_rne(a[i] - bf2f(hh));
                Ahi[(xb + i) * KSTR + c] = hh;
                Alo[(xb + i) * KSTR + c] = ll;
            }
        }
        __syncthreads();                     // A ready for this 32-chunk

        // MFMA sweep: wave w -> M-tiles {2w, 2w+1}
        s16x8 ahi[2], alo[2];
        #pragma unroll
        for (int mtl = 0; mtl < 2; ++mtl) {
            const int m  = (2 * w + mtl) * 16 + (lane & 15);
            const int ko = (lane >> 4) * 8;
            ahi[mtl] = *(const s16x8*)&Ahi[m * KSTR + ko];
            alo[mtl] = *(const s16x8*)&Alo[m * KSTR + ko];
        }
        #pragma unroll
        for (int nt = 0; nt < NT; ++nt) {
            const size_t boff = (((size_t)(kt * NT + nt)) * 16 + (lane & 15)) * 32
                              + (lane >> 4) * 8;
            const s16x8 bhi = *(const s16x8*)&Bhi[boff];
            const s16x8 blo = *(const s16x8*)&Blo[boff];
            #pragma unroll
            for (int mtl = 0; mtl < 2; ++mtl) {
                acc[mtl][nt] = __builtin_amdgcn_mfma_f32_16x16x32_bf16(alo[mtl], bhi, acc[mtl][nt], 0, 0, 0);
                acc[mtl][nt] = __builtin_amdgcn_mfma_f32_16x16x32_bf16(ahi[mtl], blo, acc[mtl][nt], 0, 0, 0);
                acc[mtl][nt] = __builtin_amdgcn_mfma_f32_16x16x32_bf16(ahi[mtl], bhi, acc[mtl][nt], 0, 0, 0);
            }
        }
    }

    // epilogue: C/D layout col=lane&15 (n), row=quad*4+reg (px within tile)
    const int n    = lane & 15;
    const int quad = lane >> 4;
    #pragma unroll
    for (int mtl = 0; mtl < 2; ++mtl) {
        #pragma unroll
        for (int nt = 0; nt < NT; ++nt) {
            const int o = nt * 16 + n;
            if ((COUT % 16 == 0) || (o < COUT)) {
                const float bv = ACT ? bias[o] : 0.0f;   // L5 has no bias
                #pragma unroll
                for (int reg = 0; reg < 4; ++reg) {
                    const int px = (2 * w + mtl) * 16 + quad * 4 + reg;
                    const float v = acc[mtl][nt][reg] + bv;
                    out[((size_t)r * W_ + px) * COUT + o] = ACT ? mish_f(v) : v;
                }
            }
        }
    }
}

// ---------------------------------------------------------------------------
extern "C" void kernel_launch(void* const* d_in, const int* in_sizes, int n_in,
                              void* d_out, int out_size, void* d_ws, size_t ws_size,
                              hipStream_t stream)
{
    (void)in_sizes; (void)n_in; (void)out_size; (void)ws_size;
    const float* prv = (const float*)d_in[0];
    const float* nxt = (const float*)d_in[1];
    const float* flo = (const float*)d_in[2];
    const float* dw0 = (const float*)d_in[3];
    const float* pw0 = (const float*)d_in[4];
    const float* b0  = (const float*)d_in[5];
    const float* dw1 = (const float*)d_in[6];
    const float* pw1 = (const float*)d_in[7];
    const float* b1  = (const float*)d_in[8];
    const float* dw2 = (const float*)d_in[9];
    const float* pw2 = (const float*)d_in[10];
    const float* b2  = (const float*)d_in[11];
    const float* dw3 = (const float*)d_in[12];
    const float* pw3 = (const float*)d_in[13];
    const float* b3  = (const float*)d_in[14];
    const float* dw4 = (const float*)d_in[15];
    const float* pw4 = (const float*)d_in[16];
    const float* b4  = (const float*)d_in[17];
    const float* dw5 = (const float*)d_in[18];
    const float* pw5 = (const float*)d_in[19];

    char* ws = (char*)d_ws;
    float* bufA = (float*)ws;                               // [0, 64Mi)
    float* bufC = (float*)(ws + 67108864);                  // [64Mi, 128Mi)
    float* costb = bufC;                                    // 42.47 MB
    float* l4out = (float*)(ws + 67108864 + 33554432);      // bufC + 32Mi (16 MB)
    float* outp  = (float*)d_out;

    // weight regions (bf16 hi/lo tile arrays)
    unsigned short* W0h = (unsigned short*)(ws + 112000000);            // 57344 B
    unsigned short* W0l = (unsigned short*)(ws + 112000000 + 57344);
    unsigned short* W1h = (unsigned short*)d_out;                       // 32768 B
    unsigned short* W1l = (unsigned short*)d_out + 16384;
    unsigned short* W2h = (unsigned short*)(ws + 50331648);             // 24576 B
    unsigned short* W2l = (unsigned short*)(ws + 50356224);
    unsigned short* W3h = (unsigned short*)(ws + 50380800);             // 12288 B
    unsigned short* W3l = (unsigned short*)(ws + 50393088);
    unsigned short* W4h = (unsigned short*)(ws + 50405376);             //  4096 B
    unsigned short* W4l = (unsigned short*)(ws + 50409472);
    unsigned short* W5h = (unsigned short*)(ws + 50413568);             //  1024 B
    unsigned short* W5l = (unsigned short*)(ws + 50414592);

    const float* nullf = nullptr;

    warp_kernel<<<65536, 256, 0, stream>>>(nxt, flo, bufA);
    costvol_kernel<<<1024, 576, 0, stream>>>(prv, bufA, costb);

    prep_kernel<<<7 * 8, 256, 0, stream>>>(pw0, 211, 128, 8, W0h, W0l);
    prep_kernel<<<4 * 8, 256, 0, stream>>>(pw1, 128, 128, 8, W1h, W1l);

    // L0: 211 -> 128, reads [cost|prv|flo], writes bufA (nxtw dead)
    sepconv_kernel<211, 128, true,  true ><<<1024, 256, 0, stream>>>(
        nullf, costb, prv, flo, dw0, W0h, W0l, b0, bufA);
    // L1: 128 -> 128, bufA -> bufC (cost + W0 dead)
    sepconv_kernel<128, 128, true,  false><<<1024, 256, 0, stream>>>(
        bufA, nullf, nullf, nullf, dw1, W1h, W1l, b1, bufC);

    // bufA now dead -> prep remaining weights into its tail
    prep_kernel<<<4 * 6, 256, 0, stream>>>(pw2, 128,  96, 6, W2h, W2l);
    prep_kernel<<<3 * 4, 256, 0, stream>>>(pw3,  96,  64, 4, W3h, W3l);
    prep_kernel<<<2 * 2, 256, 0, stream>>>(pw4,  64,  32, 2, W4h, W4l);
    prep_kernel<<<1 * 1, 256, 0, stream>>>(pw5,  32,   2, 1, W5h, W5l);

    // L2: 128 -> 96, bufC -> bufA[0,48Mi)
    sepconv_kernel<128,  96, true,  false><<<1024, 256, 0, stream>>>(
        bufC, nullf, nullf, nullf, dw2, W2h, W2l, b2, bufA);
    // L3: 96 -> 64, bufA -> bufC[0,32Mi) (L1 out dead)
    sepconv_kernel< 96,  64, true,  false><<<1024, 256, 0, stream>>>(
        bufA, nullf, nullf, nullf, dw3, W3h, W3l, b3, bufC);
    // L4: 64 -> 32, bufC[0,32Mi) -> bufC[32Mi,48Mi)
    sepconv_kernel< 64,  32, true,  false><<<1024, 256, 0, stream>>>(
        bufC, nullf, nullf, nullf, dw4, W4h, W4l, b4, l4out);
    // L5: 32 -> 2, -> d_out (overwrites W1)
    sepconv_kernel< 32,   2, false, false><<<1024, 256, 0, stream>>>(
        l4out, nullf, nullf, nullf, dw5, W5h, W5l, nullf, outp);
}

// Round 6
// 759.699 us; speedup vs baseline: 1.5640x; 1.2978x over previous
//
#include <hip/hip_runtime.h>

#define B_ 8
#define H_ 128
#define W_ 128
#define C_ 128

using f32x4 = __attribute__((ext_vector_type(4))) float;
using s16x8 = __attribute__((ext_vector_type(8))) short;

// mish(x) = x * tanh(softplus(x)) = x * (t^2 + 2t) / (t^2 + 2t + 2), t = e^x
__device__ __forceinline__ float mish_f(float x) {
    float t = __expf(fminf(x, 20.0f));
    float u = t * (t + 2.0f);
    return x * u / (u + 2.0f);
}

__device__ __forceinline__ int swz_row(int blk) {
    return ((blk & 7) << 7) | (blk >> 3);
}

// fp32 -> bf16 round-to-nearest-even on raw bits
__device__ __forceinline__ unsigned short f2bf_rne(float x) {
    unsigned u = __builtin_bit_cast(unsigned, x);
    u += 0x7FFFu + ((u >> 16) & 1u);
    return (unsigned short)(u >> 16);
}
__device__ __forceinline__ float bf2f(unsigned short h) {
    unsigned u = ((unsigned)h) << 16;
    return __builtin_bit_cast(float, u);
}

// ---------------------------------------------------------------------------
// 1) bilinear backward warp
// ---------------------------------------------------------------------------
__global__ __launch_bounds__(256) void warp_kernel(
    const float* __restrict__ nxt, const float* __restrict__ flo,
    float* __restrict__ nxtw)
{
    const int tid = threadIdx.x;
    const int c   = tid & 127;
    const int pix = blockIdx.x * 2 + (tid >> 7);
    const int b   = pix >> 14;
    const int rem = pix & 16383;
    const int y   = rem >> 7;
    const int x   = rem & 127;

    const float fx = flo[(size_t)pix * 2 + 0];
    const float fy = flo[(size_t)pix * 2 + 1];
    const float xf = (float)x + fx;
    const float yf = (float)y + fy;
    const int x0 = (int)xf;
    const int y0 = (int)yf;
    const int x0c = min(max(x0, 0), W_ - 1);
    const int x1c = min(max(x0 + 1, 0), W_ - 1);
    const int y0c = min(max(y0, 0), H_ - 1);
    const int y1c = min(max(y0 + 1, 0), H_ - 1);
    const float x0f = (float)x0c, x1f = (float)x1c;
    const float y0f = (float)y0c, y1f = (float)y1c;
    const float wa = (x1f - xf) * (y1f - yf);
    const float wb = (x1f - xf) * (yf - y0f);
    const float wc = (xf - x0f) * (y1f - yf);
    const float wd = (xf - x0f) * (yf - y0f);

    const float* base = nxt + (size_t)b * H_ * W_ * C_;
    const float Ia = base[((size_t)y0c * W_ + x0c) * C_ + c];
    const float Ib = base[((size_t)y1c * W_ + x0c) * C_ + c];
    const float Ic = base[((size_t)y0c * W_ + x1c) * C_ + c];
    const float Id = base[((size_t)y1c * W_ + x1c) * C_ + c];
    nxtw[(size_t)pix * C_ + c] = wa * Ia + wb * Ib + wc * Ic + wd * Id;
}

// ---------------------------------------------------------------------------
// 2) cost volume (R2 design — not the bottleneck)
// ---------------------------------------------------------------------------
__global__ __launch_bounds__(576, 3) void costvol_kernel(
    const float* __restrict__ prv, const float* __restrict__ nxtw,
    float* __restrict__ cost)
{
    constexpr int KC   = 8;
    constexpr int NSTR = 144;
    constexpr int PSTR = 132;
    __shared__ float NL[9][KC][NSTR];
    __shared__ float PL[KC][PSTR];

    const int tid  = threadIdx.x;
    const int w    = tid >> 6;
    const int lane = tid & 63;
    const int dy   = w - 4;
    const int r    = swz_row(blockIdx.x);
    const int y    = r & 127;
    const int b    = r >> 7;
    const int q    = y + dy;
    const bool valid = (q >= 0) && (q < H_);

    const int cs = lane & 3;
    const int xg = lane >> 2;
    const int x0 = xg * 8;

    const int scl = lane & 7;
    const int sxq = lane >> 3;
    const float* nrow = nxtw + ((size_t)(b * H_ + q) * W_) * C_;
    const int ppc = tid & 7;
    const int ppq = tid >> 3;

    float acc[8][9];
    #pragma unroll
    for (int i = 0; i < 8; ++i)
        #pragma unroll
        for (int d = 0; d < 9; ++d) acc[i][d] = 0.0f;

    float nv[5][4];
    float pv4[4];

    {
        const int c0 = 0;
        if (valid) {
            #pragma unroll
            for (int p = 0; p < 5; ++p) {
                const int xh0 = p * 32 + sxq * 4;
                if (xh0 < 140) {
                    #pragma unroll
                    for (int t = 0; t < 4; ++t) {
                        const int xs = xh0 + t - 4;
                        nv[p][t] = (xs >= 0 && xs < W_)
                                 ? nrow[(size_t)xs * C_ + c0 + scl] : 0.0f;
                    }
                }
            }
        }
        if (tid < 256) {
            #pragma unroll
            for (int t = 0; t < 4; ++t)
                pv4[t] = prv[((size_t)r * W_ + ppq * 4 + t) * C_ + c0 + ppc];
        }
    }

    for (int cc = 0; cc < 16; ++cc) {
        __syncthreads();
        if (valid) {
            #pragma unroll
            for (int p = 0; p < 5; ++p) {
                const int xh0 = p * 32 + sxq * 4;
                if (xh0 < 140)
                    *(float4*)&NL[w][scl][xh0] =
                        make_float4(nv[p][0], nv[p][1], nv[p][2], nv[p][3]);
            }
        }
        if (tid < 256)
            *(float4*)&PL[ppc][ppq * 4] =
                make_float4(pv4[0], pv4[1], pv4[2], pv4[3]);
        __syncthreads();

        if (cc < 15) {
            const int c0 = (cc + 1) * KC;
            if (valid) {
                #pragma unroll
                for (int p = 0; p < 5; ++p) {
                    const int xh0 = p * 32 + sxq * 4;
                    if (xh0 < 140) {
                        #pragma unroll
                        for (int t = 0; t < 4; ++t) {
                            const int xs = xh0 + t - 4;
                            nv[p][t] = (xs >= 0 && xs < W_)
                                     ? nrow[(size_t)xs * C_ + c0 + scl] : 0.0f;
                        }
                    }
                }
            }
            if (tid < 256) {
                #pragma unroll
                for (int t = 0; t < 4; ++t)
                    pv4[t] = prv[((size_t)r * W_ + ppq * 4 + t) * C_ + c0 + ppc];
            }
        }

        if (valid) {
            #pragma unroll
            for (int j = 0; j < 2; ++j) {
                const int c = cs + 4 * j;
                float pv[8];
                {
                    float4 p0 = *(const float4*)&PL[c][x0];
                    float4 p1 = *(const float4*)&PL[c][x0 + 4];
                    pv[0]=p0.x; pv[1]=p0.y; pv[2]=p0.z; pv[3]=p0.w;
                    pv[4]=p1.x; pv[5]=p1.y; pv[6]=p1.z; pv[7]=p1.w;
                }
                float n[16];
                {
                    float4 n0 = *(const float4*)&NL[w][c][x0];
                    float4 n1 = *(const float4*)&NL[w][c][x0 + 4];
                    float4 n2 = *(const float4*)&NL[w][c][x0 + 8];
                    float4 n3 = *(const float4*)&NL[w][c][x0 + 12];
                    n[0]=n0.x;  n[1]=n0.y;  n[2]=n0.z;  n[3]=n0.w;
                    n[4]=n1.x;  n[5]=n1.y;  n[6]=n1.z;  n[7]=n1.w;
                    n[8]=n2.x;  n[9]=n2.y;  n[10]=n2.z; n[11]=n2.w;
                    n[12]=n3.x; n[13]=n3.y; n[14]=n3.z; n[15]=n3.w;
                }
                #pragma unroll
                for (int i = 0; i < 8; ++i)
                    #pragma unroll
                    for (int d = 0; d < 9; ++d)
                        acc[i][d] += pv[i] * n[i + d];
            }
        }
    }

    #pragma unroll
    for (int i = 0; i < 8; ++i)
        #pragma unroll
        for (int d = 0; d < 9; ++d) {
            float v = acc[i][d];
            v += __shfl_xor(v, 1);
            v += __shfl_xor(v, 2);
            acc[i][d] = v;
        }
    if (cs == 0) {
        #pragma unroll
        for (int i = 0; i < 8; ++i) {
            const size_t base = ((size_t)r * W_ + (x0 + i)) * 81 + (size_t)(dy + 4) * 9;
            #pragma unroll
            for (int d = 0; d < 9; ++d)
                cost[base + d] = valid ? acc[i][d] * (1.0f / 128.0f) : 0.0f;
        }
    }
}

// ---------------------------------------------------------------------------
// 3) weight prep: pw[CIN][COUT] fp32 -> bf16 hi/lo B-frag tiles
// ---------------------------------------------------------------------------
__global__ __launch_bounds__(256) void prep_kernel(
    const float* __restrict__ pw, int CIN, int COUT, int NT,
    unsigned short* __restrict__ hi, unsigned short* __restrict__ lo)
{
    const int kt = blockIdx.x / NT;
    const int nt = blockIdx.x - kt * NT;
    #pragma unroll
    for (int s = 0; s < 2; ++s) {
        const int e = threadIdx.x + 256 * s;
        const int n = e >> 5, k = e & 31;
        const int kg = kt * 32 + k, ng = nt * 16 + n;
        const float v = (kg < CIN && ng < COUT) ? pw[(size_t)kg * COUT + ng] : 0.0f;
        const unsigned short h = f2bf_rne(v);
        const unsigned short l = f2bf_rne(v - bf2f(h));
        const size_t o = ((size_t)blockIdx.x * 16 + n) * 32 + k;
        hi[o] = h; lo[o] = l;
    }
}

// ---------------------------------------------------------------------------
// 4) fused depthwise3x3(fp32) + pointwise MFMA (bf16 hi/lo), one block/row.
// 512 threads (8 waves, wave w owns M-tile w), __launch_bounds__(512,4):
// still 2 blocks/CU (same LLC residency as R5 — do NOT raise block count/CU),
// but 16 waves/CU for 2x latency hiding. Tap loads: region pointer+stride
// resolved once per task; interior px groups use constant-offset loads with
// no bounds checks; invalid rows get zeroed weights + clamped addresses.
// ---------------------------------------------------------------------------
template<int CIN, int COUT, bool ACT, bool IS_L0>
__global__ __launch_bounds__(512, 4) void sepconv_kernel(
    const float* __restrict__ in,
    const float* __restrict__ cost, const float* __restrict__ prv,
    const float* __restrict__ flo,
    const float* __restrict__ dw,
    const unsigned short* __restrict__ Bhi, const unsigned short* __restrict__ Blo,
    const float* __restrict__ bias, float* __restrict__ out)
{
    constexpr int KT   = (CIN + 31) / 32;
    constexpr int KPAD = KT * 32;
    constexpr int NT   = (COUT + 15) / 16;
    constexpr int KSTR = 40;                 // ushort stride per px (80B, 16B-mult)
    __shared__ unsigned short Ahi[128 * KSTR];   // 10240 B
    __shared__ unsigned short Alo[128 * KSTR];   // 10240 B
    __shared__ float dwl[9 * KPAD];              // <= 8064 B

    const int tid  = threadIdx.x;
    const int lane = tid & 63;
    const int w    = tid >> 6;               // wave 0..7
    const int r    = swz_row(blockIdx.x);    // b*H + h
    const int h    = r & 127;
    const int b    = r >> 7;

    // stage all depthwise weights once (zero-padded channels)
    for (int i = tid; i < 9 * KPAD; i += 512) {
        const int t = i / KPAD, c = i - t * KPAD;
        dwl[i] = (c < CIN) ? dw[t * CIN + c] : 0.0f;
    }

    f32x4 acc[NT];
    #pragma unroll
    for (int n = 0; n < NT; ++n)
        acc[n] = (f32x4){0.0f, 0.0f, 0.0f, 0.0f};

    for (int kt = 0; kt < KT; ++kt) {
        __syncthreads();                     // dwl ready / prev MFMA A-reads done

        // depthwise: 2 tasks/thread; task = (c in [0,32), 4-px group)
        #pragma unroll
        for (int s = 0; s < 2; ++s) {
            const int e   = tid + 512 * s;
            const int c   = e & 31;
            const int pxg = (e >> 5) & 31;
            const int xb  = pxg * 4;
            const int cg  = kt * 32 + c;

            // resolve source region + stride once per task
            const float* src; int stride;
            if constexpr (IS_L0) {
                if (cg < 81)       { src = cost + cg;              stride = 81;  }
                else if (cg < 209) { src = prv + (cg - 81);        stride = 128; }
                else               { src = flo + min(cg - 209, 1); stride = 2;   }
            } else {
                src = in + cg; stride = CIN;
            }

            // per-row base pointers + weights (invalid rows: zero weight,
            // clamped in-bounds address)
            const float* rp[3];
            float wk[9];
            #pragma unroll
            for (int ky = 0; ky < 3; ++ky) {
                const int yy  = h + ky - 1;
                const bool yok = (yy >= 0) & (yy < H_);
                const int yc  = yok ? yy : h;
                rp[ky] = src + (size_t)((b * H_ + yc) * W_) * stride;
                #pragma unroll
                for (int kx = 0; kx < 3; ++kx)
                    wk[ky * 3 + kx] = yok ? dwl[(ky * 3 + kx) * KPAD + kt * 32 + c] : 0.0f;
            }

            float a[4] = {0.f, 0.f, 0.f, 0.f};
            if (xb != 0 && xb != 124) {
                // interior: 6 unguarded loads per row at constant offsets
                #pragma unroll
                for (int ky = 0; ky < 3; ++ky) {
                    const float* p = rp[ky] + (size_t)(xb - 1) * stride;
                    float v[6];
                    #pragma unroll
                    for (int m = 0; m < 6; ++m) v[m] = p[(size_t)m * stride];
                    #pragma unroll
                    for (int i = 0; i < 4; ++i)
                        a[i] = wk[0] * v[i] + wk[1] * v[i + 1] + wk[2] * v[i + 2]
                             + a[i];
                    // rows 1,2 accumulate below via separate weight taps
                    if (ky == 0) { /* handled above with wk[0..2] */ }
                    else { }
                    // NOTE: generic form below replaces this — see loop rewrite
                }
                // redo properly with per-row taps (compiler folds duplicates)
                a[0] = a[1] = a[2] = a[3] = 0.f;
                #pragma unroll
                for (int ky = 0; ky < 3; ++ky) {
                    const float* p = rp[ky] + (size_t)(xb - 1) * stride;
                    float v[6];
                    #pragma unroll
                    for (int m = 0; m < 6; ++m) v[m] = p[(size_t)m * stride];
                    #pragma unroll
                    for (int i = 0; i < 4; ++i)
                        a[i] += wk[ky * 3 + 0] * v[i]
                              + wk[ky * 3 + 1] * v[i + 1]
                              + wk[ky * 3 + 2] * v[i + 2];
                }
            } else {
                #pragma unroll
                for (int ky = 0; ky < 3; ++ky) {
                    #pragma unroll
                    for (int m = 0; m < 6; ++m) {
                        const int xx = xb - 1 + m;
                        const int xc = min(max(xx, 0), W_ - 1);
                        const bool ok = (xx >= 0) & (xx < W_);
                        float v = rp[ky][(size_t)xc * stride];
                        v = ok ? v : 0.0f;
                        #pragma unroll
                        for (int kx = 0; kx < 3; ++kx) {
                            const int i = m - kx;
                            if (i >= 0 && i < 4) a[i] += wk[ky * 3 + kx] * v;
                        }
                    }
                }
            }
            #pragma unroll
            for (int i = 0; i < 4; ++i) {
                const unsigned short hh = f2bf_rne(a[i]);
                const unsigned short ll = f2bf_rne(a[i] - bf2f(hh));
                Ahi[(xb + i) * KSTR + c] = hh;
                Alo[(xb + i) * KSTR + c] = ll;
            }
        }
        __syncthreads();                     // A ready for this 32-chunk

        // MFMA sweep: wave w -> M-tile w
        const int mrow = w * 16 + (lane & 15);
        const int ko   = (lane >> 4) * 8;
        const s16x8 ahi = *(const s16x8*)&Ahi[mrow * KSTR + ko];
        const s16x8 alo = *(const s16x8*)&Alo[mrow * KSTR + ko];
        #pragma unroll
        for (int nt = 0; nt < NT; ++nt) {
            const size_t boff = (((size_t)(kt * NT + nt)) * 16 + (lane & 15)) * 32
                              + (size_t)ko;
            const s16x8 bhi = *(const s16x8*)&Bhi[boff];
            const s16x8 blo = *(const s16x8*)&Blo[boff];
            acc[nt] = __builtin_amdgcn_mfma_f32_16x16x32_bf16(alo, bhi, acc[nt], 0, 0, 0);
            acc[nt] = __builtin_amdgcn_mfma_f32_16x16x32_bf16(ahi, blo, acc[nt], 0, 0, 0);
            acc[nt] = __builtin_amdgcn_mfma_f32_16x16x32_bf16(ahi, bhi, acc[nt], 0, 0, 0);
        }
    }

    // epilogue: C/D layout col=lane&15 (n), row=quad*4+reg (px within tile)
    const int n    = lane & 15;
    const int quad = lane >> 4;
    #pragma unroll
    for (int nt = 0; nt < NT; ++nt) {
        const int o = nt * 16 + n;
        if ((COUT % 16 == 0) || (o < COUT)) {
            const float bv = ACT ? bias[o] : 0.0f;   // L5 has no bias
            #pragma unroll
            for (int reg = 0; reg < 4; ++reg) {
                const int px = w * 16 + quad * 4 + reg;
                const float v = acc[nt][reg] + bv;
                out[((size_t)r * W_ + px) * COUT + o] = ACT ? mish_f(v) : v;
            }
        }
    }
}

// ---------------------------------------------------------------------------
extern "C" void kernel_launch(void* const* d_in, const int* in_sizes, int n_in,
                              void* d_out, int out_size, void* d_ws, size_t ws_size,
                              hipStream_t stream)
{
    (void)in_sizes; (void)n_in; (void)out_size; (void)ws_size;
    const float* prv = (const float*)d_in[0];
    const float* nxt = (const float*)d_in[1];
    const float* flo = (const float*)d_in[2];
    const float* dw0 = (const float*)d_in[3];
    const float* pw0 = (const float*)d_in[4];
    const float* b0  = (const float*)d_in[5];
    const float* dw1 = (const float*)d_in[6];
    const float* pw1 = (const float*)d_in[7];
    const float* b1  = (const float*)d_in[8];
    const float* dw2 = (const float*)d_in[9];
    const float* pw2 = (const float*)d_in[10];
    const float* b2  = (const float*)d_in[11];
    const float* dw3 = (const float*)d_in[12];
    const float* pw3 = (const float*)d_in[13];
    const float* b3  = (const float*)d_in[14];
    const float* dw4 = (const float*)d_in[15];
    const float* pw4 = (const float*)d_in[16];
    const float* b4  = (const float*)d_in[17];
    const float* dw5 = (const float*)d_in[18];
    const float* pw5 = (const float*)d_in[19];

    char* ws = (char*)d_ws;
    float* bufA = (float*)ws;                               // [0, 64Mi)
    float* bufC = (float*)(ws + 67108864);                  // [64Mi, 128Mi)
    float* costb = bufC;                                    // 42.47 MB
    float* l4out = (float*)(ws + 67108864 + 33554432);      // bufC + 32Mi (16 MB)
    float* outp  = (float*)d_out;

    // weight regions (bf16 hi/lo tile arrays)
    unsigned short* W0h = (unsigned short*)(ws + 112000000);            // 57344 B
    unsigned short* W0l = (unsigned short*)(ws + 112000000 + 57344);
    unsigned short* W1h = (unsigned short*)d_out;                       // 32768 B
    unsigned short* W1l = (unsigned short*)d_out + 16384;
    unsigned short* W2h = (unsigned short*)(ws + 50331648);             // 24576 B
    unsigned short* W2l = (unsigned short*)(ws + 50356224);
    unsigned short* W3h = (unsigned short*)(ws + 50380800);             // 12288 B
    unsigned short* W3l = (unsigned short*)(ws + 50393088);
    unsigned short* W4h = (unsigned short*)(ws + 50405376);             //  4096 B
    unsigned short* W4l = (unsigned short*)(ws + 50409472);
    unsigned short* W5h = (unsigned short*)(ws + 50413568);             //  1024 B
    unsigned short* W5l = (unsigned short*)(ws + 50414592);

    const float* nullf = nullptr;

    warp_kernel<<<65536, 256, 0, stream>>>(nxt, flo, bufA);
    costvol_kernel<<<1024, 576, 0, stream>>>(prv, bufA, costb);

    prep_kernel<<<7 * 8, 256, 0, stream>>>(pw0, 211, 128, 8, W0h, W0l);
    prep_kernel<<<4 * 8, 256, 0, stream>>>(pw1, 128, 128, 8, W1h, W1l);

    // L0: 211 -> 128, reads [cost|prv|flo], writes bufA (nxtw dead)
    sepconv_kernel<211, 128, true,  true ><<<1024, 512, 0, stream>>>(
        nullf, costb, prv, flo, dw0, W0h, W0l, b0, bufA);
    // L1: 128 -> 128, bufA -> bufC (cost + W0 dead)
    sepconv_kernel<128, 128, true,  false><<<1024, 512, 0, stream>>>(
        bufA, nullf, nullf, nullf, dw1, W1h, W1l, b1, bufC);

    // bufA now dead -> prep remaining weights into its tail
    prep_kernel<<<4 * 6, 256, 0, stream>>>(pw2, 128,  96, 6, W2h, W2l);
    prep_kernel<<<3 * 4, 256, 0, stream>>>(pw3,  96,  64, 4, W3h, W3l);
    prep_kernel<<<2 * 2, 256, 0, stream>>>(pw4,  64,  32, 2, W4h, W4l);
    prep_kernel<<<1 * 1, 256, 0, stream>>>(pw5,  32,   2, 1, W5h, W5l);

    // L2: 128 -> 96, bufC -> bufA[0,48Mi)
    sepconv_kernel<128,  96, true,  false><<<1024, 512, 0, stream>>>(
        bufC, nullf, nullf, nullf, dw2, W2h, W2l, b2, bufA);
    // L3: 96 -> 64, bufA -> bufC[0,32Mi) (L1 out dead)
    sepconv_kernel< 96,  64, true,  false><<<1024, 512, 0, stream>>>(
        bufA, nullf, nullf, nullf, dw3, W3h, W3l, b3, bufC);
    // L4: 64 -> 32, bufC[0,32Mi) -> bufC[32Mi,48Mi)
    sepconv_kernel< 64,  32, true,  false><<<1024, 512, 0, stream>>>(
        bufC, nullf, nullf, nullf, dw4, W4h, W4l, b4, l4out);
    // L5: 32 -> 2, -> d_out (overwrites W1)
    sepconv_kernel< 32,   2, false, false><<<1024, 512, 0, stream>>>(
        l4out, nullf, nullf, nullf, dw5, W5h, W5l, nullf, outp);
}